// Round 13
// baseline (716.272 us; speedup 1.0000x reference)
//
#include <hip/hip_runtime.h>
#include <hip/hip_bf16.h>
#include <math.h>

#define DEV __device__ __forceinline__

typedef __bf16 bf16x8 __attribute__((ext_vector_type(8)));
typedef float f32x4 __attribute__((ext_vector_type(4)));
typedef unsigned short ushort_t;
typedef ushort_t us8 __attribute__((ext_vector_type(8)));
typedef ushort_t us4 __attribute__((ext_vector_type(4)));

DEV float bf2f(ushort_t u) {
    unsigned v = ((unsigned)u) << 16;
    float f; __builtin_memcpy(&f, &v, 4); return f;
}
DEV ushort_t f2bf(float f) {
    __bf16 h = (__bf16)f;
    ushort_t u; __builtin_memcpy(&u, &h, 2); return u;
}

DEV void gload16(const void* g, void* l) {
    __builtin_amdgcn_global_load_lds(
        (const __attribute__((address_space(1))) void*)g,
        (__attribute__((address_space(3))) void*)l, 16, 0, 0);
}

#define WAITV(n)  asm volatile("s_waitcnt vmcnt(" #n ")" ::: "memory")
#define WAITL0()  asm volatile("s_waitcnt lgkmcnt(0)" ::: "memory")
#define BAR()     __builtin_amdgcn_s_barrier()
#define SB0()     __builtin_amdgcn_sched_barrier(0)

// ---------------- sentinel fill ----------------
__global__ __launch_bounds__(256) void fill_kernel(float* out, long n, float v) {
    long i = (long)blockIdx.x * blockDim.x + threadIdx.x;
    if (i < n) out[i] = v;
}

// ---------------- cast f32 -> bf16 ----------------
__global__ __launch_bounds__(256) void cast_bf16_kernel(
    const float* __restrict__ in, ushort_t* __restrict__ out, long n)
{
    long i = ((long)blockIdx.x * blockDim.x + threadIdx.x) * 4;
    if (i >= n) return;
    float4 v = *(const float4*)(in + i);
    us4 o = { f2bf(v.x), f2bf(v.y), f2bf(v.z), f2bf(v.w) };
    *(us4*)(out + i) = o;
}

// ---------------- transpose + cast ----------------
__global__ __launch_bounds__(256) void transpose_bf16_kernel(
    const float* __restrict__ in, ushort_t* __restrict__ out, int R, int C)
{
    __shared__ float tile[32][33];
    int c0 = blockIdx.x * 32, r0 = blockIdx.y * 32;
    int tx = threadIdx.x & 31, ty = threadIdx.x >> 5;
#pragma unroll
    for (int j = 0; j < 4; ++j) {
        int r = ty + j * 8;
        tile[r][tx] = in[(long)(r0 + r) * C + (c0 + tx)];
    }
    __syncthreads();
#pragma unroll
    for (int j = 0; j < 4; ++j) {
        int r = ty + j * 8;
        out[(long)(c0 + r) * R + (r0 + tx)] = f2bf(tile[tx][r]);
    }
}

// ---------------- merged 3-way transpose ----------------
__global__ __launch_bounds__(256) void transpose3_bf16_kernel(
    const float* __restrict__ w0, const float* __restrict__ w1,
    const float* __restrict__ w2, ushort_t* __restrict__ out)
{
    __shared__ float tile[32][33];
    const float* in = (blockIdx.z == 0) ? w0 : (blockIdx.z == 1) ? w1 : w2;
    ushort_t* o = out + (size_t)blockIdx.z * 2048 * 2048;
    int c0 = blockIdx.x * 32, r0 = blockIdx.y * 32;
    int tx = threadIdx.x & 31, ty = threadIdx.x >> 5;
#pragma unroll
    for (int j = 0; j < 4; ++j) {
        int r = ty + j * 8;
        tile[r][tx] = in[(long)(r0 + r) * 2048 + (c0 + tx)];
    }
    __syncthreads();
#pragma unroll
    for (int j = 0; j < 4; ++j) {
        int r = ty + j * 8;
        o[(long)(c0 + r) * 2048 + (r0 + tx)] = f2bf(tile[tx][r]);
    }
}

// Coalesced epilogue (64x32 LDS transpose per wave, 72B stride, full-sector stores)
DEV void epilogue_store(f32x4 (&acc)[4][4], const float* bias, ushort_t* C,
                        long m0, long n0, int N, int act, int wr, int wc, int l,
                        char* lwb)
{
    ushort_t* lw = (ushort_t*)lwb;
#pragma unroll
    for (int jj = 0; jj < 2; ++jj) {
#pragma unroll
        for (int jh = 0; jh < 2; ++jh) {
            int j = jj * 2 + jh;
            int col = (int)n0 + wc * 64 + j * 16 + (l & 15);
            float bv = bias[col];
#pragma unroll
            for (int i = 0; i < 4; ++i) {
#pragma unroll
                for (int r = 0; r < 4; ++r) {
                    float v2 = acc[i][j][r] + bv;
                    if (act == 1) v2 = 0.5f * v2 * (1.f + erff(v2 * 0.70710678118654752440f));
                    lw[(i * 16 + (l >> 4) * 4 + r) * 36 + jh * 16 + (l & 15)] = f2bf(v2);
                }
            }
        }
        WAITL0();
#pragma unroll
        for (int p = 0; p < 8; ++p) {
            int row = p * 8 + (l >> 3);
            us4 vv = *(const us4*)(lw + row * 36 + (l & 7) * 4);
            *(us4*)(C + (m0 + wr * 64 + row) * (long)N + n0 + wc * 64 + jj * 32 + (l & 7) * 4) = vv;
        }
        WAITL0();
    }
}

// ---------------- GEMM 128x128, BK=64 (proven fallback) ----------
__global__ __launch_bounds__(256) void gemm_bt_kernel(
    const ushort_t* __restrict__ A, const ushort_t* __restrict__ Bt,
    const float* __restrict__ bias, ushort_t* __restrict__ C,
    int M, int N, int K, int act)
{
    __shared__ __align__(16) ushort_t lA[128 * 64];
    __shared__ __align__(16) ushort_t lB[128 * 64];
    const int t = threadIdx.x;
    const int w = t >> 6, l = t & 63;
    const int wr = w >> 1, wc = w & 1;
    const long m0 = (long)blockIdx.x * 128;
    const long n0 = (long)blockIdx.y * 128;

    const int sr = l >> 3;
    const int scol = (l & 7) * 16;

    f32x4 acc[4][4];
    f32x4 zf = {0.f, 0.f, 0.f, 0.f};
#pragma unroll
    for (int i = 0; i < 4; ++i)
#pragma unroll
        for (int j = 0; j < 4; ++j) acc[i][j] = zf;

    char* lAc = (char*)lA;
    char* lBc = (char*)lB;

    const char* aptr[4];
    const char* bptr[4];
#pragma unroll
    for (int c = 0; c < 4; ++c) {
        int row = (w * 4 + c) * 8 + sr;
        int src = scol ^ ((row & 7) << 4);
        aptr[c] = (const char*)(A + (m0 + row) * (long)K) + src;
        bptr[c] = (const char*)(Bt + (n0 + row) * (long)K) + src;
    }

    for (int k0 = 0; k0 < K; k0 += 64) {
        __syncthreads();
#pragma unroll
        for (int c = 0; c < 4; ++c) {
            gload16(aptr[c], lAc + (w * 4 + c) * 1024);
            gload16(bptr[c], lBc + (w * 4 + c) * 1024);
            aptr[c] += 128;
            bptr[c] += 128;
        }
        __syncthreads();
#pragma unroll
        for (int ks = 0; ks < 2; ++ks) {
            bf16x8 af[4], bfr[4];
#pragma unroll
            for (int i = 0; i < 4; ++i) {
                int row = wr * 64 + i * 16 + (l & 15);
                int cb = (ks * 64 + (l >> 4) * 16) ^ ((row & 7) << 4);
                af[i] = *(const bf16x8*)(lAc + row * 128 + cb);
            }
#pragma unroll
            for (int j = 0; j < 4; ++j) {
                int row = wc * 64 + j * 16 + (l & 15);
                int cb = (ks * 64 + (l >> 4) * 16) ^ ((row & 7) << 4);
                bfr[j] = *(const bf16x8*)(lBc + row * 128 + cb);
            }
#pragma unroll
            for (int i = 0; i < 4; ++i)
#pragma unroll
                for (int j = 0; j < 4; ++j)
                    acc[i][j] = __builtin_amdgcn_mfma_f32_16x16x32_bf16(af[i], bfr[j], acc[i][j], 0, 0, 0);
        }
    }

    __syncthreads();
    epilogue_store(acc, bias, C, m0, n0, N, act, wr, wc, l,
                   (w < 2 ? lAc : lBc) + (w & 1) * 4608);
}

// ---------------- GEMM 128x128, BK=128 (grid-limited dispatches) ----
__global__ __launch_bounds__(256) void gemm_bt128_kernel(
    const ushort_t* __restrict__ A, const ushort_t* __restrict__ Bt,
    const float* __restrict__ bias, ushort_t* __restrict__ C,
    int M, int N, int K, int act)
{
    __shared__ __align__(16) ushort_t lA[128 * 128];   // 32KB
    __shared__ __align__(16) ushort_t lB[128 * 128];   // 32KB
    const int t = threadIdx.x;
    const int w = t >> 6, l = t & 63;
    const int wr = w >> 1, wc = w & 1;
    const long m0 = (long)blockIdx.x * 128;
    const long n0 = (long)blockIdx.y * 128;

    const int srow = t >> 4;
    const int ssrc = ((t & 15) * 16) ^ ((srow & 7) << 4);

    f32x4 acc[4][4];
    f32x4 zf = {0.f, 0.f, 0.f, 0.f};
#pragma unroll
    for (int i = 0; i < 4; ++i)
#pragma unroll
        for (int j = 0; j < 4; ++j) acc[i][j] = zf;

    char* lAc = (char*)lA;
    char* lBc = (char*)lB;

    const char* aptr[8];
    const char* bptr[8];
#pragma unroll
    for (int r = 0; r < 8; ++r) {
        int row = r * 16 + srow;
        aptr[r] = (const char*)(A + (m0 + row) * (long)K) + ssrc;
        bptr[r] = (const char*)(Bt + (n0 + row) * (long)K) + ssrc;
    }

    for (int k0 = 0; k0 < K; k0 += 128) {
        __syncthreads();
#pragma unroll
        for (int r = 0; r < 8; ++r) {
            gload16(aptr[r], lAc + r * 4096 + t * 16);
            gload16(bptr[r], lBc + r * 4096 + t * 16);
            aptr[r] += 256;
            bptr[r] += 256;
        }
        __syncthreads();
#pragma unroll
        for (int ks = 0; ks < 4; ++ks) {
            bf16x8 af[4], bfr[4];
#pragma unroll
            for (int i = 0; i < 4; ++i) {
                int row = wr * 64 + i * 16 + (l & 15);
                int cb = (ks * 64 + (l >> 4) * 16) ^ ((row & 7) << 4);
                af[i] = *(const bf16x8*)(lAc + row * 256 + cb);
            }
#pragma unroll
            for (int j = 0; j < 4; ++j) {
                int row = wc * 64 + j * 16 + (l & 15);
                int cb = (ks * 64 + (l >> 4) * 16) ^ ((row & 7) << 4);
                bfr[j] = *(const bf16x8*)(lBc + row * 256 + cb);
            }
#pragma unroll
            for (int i = 0; i < 4; ++i)
#pragma unroll
                for (int j = 0; j < 4; ++j)
                    acc[i][j] = __builtin_amdgcn_mfma_f32_16x16x32_bf16(af[i], bfr[j], acc[i][j], 0, 0, 0);
        }
    }

    __syncthreads();
    epilogue_store(acc, bias, C, m0, n0, N, act, wr, wc, l,
                   (w < 2 ? lAc : lBc) + (w & 1) * 4608);
}

// ---------------- GEMM 256x256 8-phase (m201 port, acc-index FIXED) ----------
// 512 thr = 8 waves (2M x 4N), per-wave 128x64 (8x4 frags). BK=64, LDS 128KB:
// [dbuf][half][128 rows][64 K] per operand. dbuf = tile parity. Both K-tiles of
// an iteration ACCUMULATE into the same acc quads (0,0),(0,1),(1,1),(1,0) --
// R12's bug was indexing acc by tile (OOB). Stage rotation (legal by slot
// lifetimes: A-slots last read @p3, B-slots @p2 within each 4-phase group):
//   p1:A0(2j+1) p2:A1(2j+1) p3:B0(2j+2) p4:B1(2j+2)+vmcnt(4)
//   p5:A0(2j+2) p6:A1(2j+2) p7:B0(2j+3) p8:B1(2j+3)+vmcnt(4)
__global__ __launch_bounds__(512, 2) void gemm8p_kernel(
    const ushort_t* __restrict__ A, const ushort_t* __restrict__ Bt,
    const float* __restrict__ bias, ushort_t* __restrict__ C,
    int M, int N, int K, int act)
{
    __shared__ __align__(16) ushort_t lA[2 * 2 * 128 * 64];   // 64KB
    __shared__ __align__(16) ushort_t lB[2 * 2 * 128 * 64];   // 64KB
    const int t = threadIdx.x, l = t & 63, w = t >> 6;
    const int wr = w >> 2, wc = w & 3;           // 2(M) x 4(N)
    const long m0 = (long)blockIdx.x * 256;
    const long n0 = (long)blockIdx.y * 256;
    char* lAc = (char*)lA;
    char* lBc = (char*)lB;

    const int rl = l & 15, rh = (l >> 4) * 16;
    const int swz = (rl & 7) << 4;
    const long KB = (long)K * 2;
    const long R64 = 64 * KB;
    const int ssrc = ((t & 7) * 16) ^ (((t >> 3) & 7) << 4);

    f32x4 acc[8][4];
    f32x4 zf = {0.f, 0.f, 0.f, 0.f};
#pragma unroll
    for (int i = 0; i < 8; ++i)
#pragma unroll
        for (int j = 0; j < 4; ++j) acc[i][j] = zf;

    const char* pA0 = (const char*)A + (m0 + (t >> 3)) * KB + ssrc;
    const char* pA1 = (const char*)A + (m0 + 128 + (t >> 3)) * KB + ssrc;
    const char* pB0 = (const char*)Bt + (n0 + (t >> 3)) * KB + ssrc;
    const char* pB1 = (const char*)Bt + (n0 + 128 + (t >> 3)) * KB + ssrc;

    auto stage = [&](const char*& p, char* dst) {
        gload16(p, dst + t * 16);
        gload16(p + R64, dst + 8192 + t * 16);
        p += 128;
    };
    auto loadA = [&](bf16x8 (&aF)[4][2], int d, int qm) {
#pragma unroll
        for (int i = 0; i < 4; ++i) {
            int rb = d * 32768 + wr * 16384 + ((qm * 4 + i) * 16 + rl) * 128;
            aF[i][0] = *(const bf16x8*)(lAc + rb + (rh ^ swz));
            aF[i][1] = *(const bf16x8*)(lAc + rb + ((64 + rh) ^ swz));
        }
    };
    auto loadB = [&](bf16x8 (&bF)[2][2], int d, int qn) {
#pragma unroll
        for (int jb = 0; jb < 2; ++jb) {
            int cih = (wc & 1) * 64 + (qn * 2 + jb) * 16 + rl;
            int rb = d * 32768 + (wc >> 1) * 16384 + cih * 128;
            bF[jb][0] = *(const bf16x8*)(lBc + rb + (rh ^ swz));
            bF[jb][1] = *(const bf16x8*)(lBc + rb + ((64 + rh) ^ swz));
        }
    };

    bf16x8 aF[4][2], bF0[2][2], bF1[2][2];
    // qm,qn in {0,1}: acc quad indices. SAME quads for both K-tiles (K accumulates).
    auto mfma16 = [&](int qm, int qn, bf16x8 (&bF)[2][2]) {
        __builtin_amdgcn_s_setprio(1);
#pragma unroll
        for (int i = 0; i < 4; ++i)
#pragma unroll
            for (int jb = 0; jb < 2; ++jb)
#pragma unroll
                for (int ks = 0; ks < 2; ++ks)
                    acc[qm * 4 + i][qn * 2 + jb] = __builtin_amdgcn_mfma_f32_16x16x32_bf16(
                        aF[i][ks], bF[jb][ks], acc[qm * 4 + i][qn * 2 + jb], 0, 0, 0);
        __builtin_amdgcn_s_setprio(0);
    };

    const int NT = K >> 6;
    // prologue: tile0 {B0,B1,A0,A1} -> dbuf0, tile1 {B0,B1} -> dbuf1; gate tile0
    stage(pB0, lBc);
    stage(pB1, lBc + 16384);
    stage(pA0, lAc);
    stage(pA1, lAc + 16384);
    stage(pB0, lBc + 32768);
    stage(pB1, lBc + 32768 + 16384);
    WAITV(4);
    SB0();
    BAR();

    const int NI = NT >> 1;
    for (int j = 0; j < NI; ++j) {
        const bool s2 = (2 * j + 2 < NT);
        // ---- p1: tile 2j quad(0,0); stage A0(2j+1)->dbuf1 h0 ----
        loadA(aF, 0, 0);
        loadB(bF0, 0, 0);
        stage(pA0, lAc + 32768);
        BAR(); WAITL0(); SB0();
        mfma16(0, 0, bF0);
        BAR();
        // ---- p2: quad(0,1); stage A1(2j+1)->dbuf1 h1 ----
        loadB(bF1, 0, 1);
        stage(pA1, lAc + 32768 + 16384);
        BAR(); WAITL0(); SB0();
        mfma16(0, 1, bF1);
        BAR();
        // ---- p3: quad(1,1); stage B0(2j+2)->dbuf0 h0 ----
        loadA(aF, 0, 1);
        if (s2) stage(pB0, lBc);
        BAR(); WAITL0(); SB0();
        mfma16(1, 1, bF1);
        BAR();
        // ---- p4: quad(1,0); stage B1(2j+2)->dbuf0 h1; gate ----
        if (s2) stage(pB1, lBc + 16384);
        BAR();
        mfma16(1, 0, bF0);
        if (s2) { WAITV(4); } else { WAITV(0); }
        SB0();
        BAR();
        // ---- p5: tile 2j+1 quad(0,0) from dbuf1; stage A0(2j+2)->dbuf0 h0 ----
        loadA(aF, 1, 0);
        loadB(bF0, 1, 0);
        if (s2) stage(pA0, lAc);
        BAR(); WAITL0(); SB0();
        mfma16(0, 0, bF0);
        BAR();
        // ---- p6: quad(0,1); stage A1(2j+2)->dbuf0 h1 ----
        loadB(bF1, 1, 1);
        if (s2) stage(pA1, lAc + 16384);
        BAR(); WAITL0(); SB0();
        mfma16(0, 1, bF1);
        BAR();
        // ---- p7: quad(1,1); stage B0(2j+3)->dbuf1 h0 ----
        loadA(aF, 1, 1);
        if (s2) stage(pB0, lBc + 32768);
        BAR(); WAITL0(); SB0();
        mfma16(1, 1, bF1);
        BAR();
        // ---- p8: quad(1,0); stage B1(2j+3)->dbuf1 h1; gate ----
        if (s2) stage(pB1, lBc + 32768 + 16384);
        BAR();
        mfma16(1, 0, bF0);
        if (s2) { WAITV(4); } else { WAITV(0); }
        SB0();
        BAR();
    }

    // epilogue: per-wave 128x64 -> two 64x64 halves via LDS-transpose store
    {
        char* lwb = lAc + w * 4608;
        ushort_t* lw = (ushort_t*)lwb;
#pragma unroll
        for (int hh = 0; hh < 2; ++hh) {
            long m0w = m0 + wr * 128 + hh * 64;
            long n0w = n0 + wc * 64;
#pragma unroll
            for (int jj = 0; jj < 2; ++jj) {
#pragma unroll
                for (int jh = 0; jh < 2; ++jh) {
                    int jf = jj * 2 + jh;
                    float bv = bias[(int)n0w + jf * 16 + rl];
#pragma unroll
                    for (int i = 0; i < 4; ++i) {
#pragma unroll
                        for (int r = 0; r < 4; ++r) {
                            float v2 = acc[hh * 4 + i][jf][r] + bv;
                            if (act == 1) v2 = 0.5f * v2 * (1.f + erff(v2 * 0.70710678118654752440f));
                            lw[(i * 16 + (l >> 4) * 4 + r) * 36 + jh * 16 + rl] = f2bf(v2);
                        }
                    }
                }
                WAITL0();
#pragma unroll
                for (int p = 0; p < 8; ++p) {
                    int row = p * 8 + (l >> 3);
                    us4 vv = *(const us4*)(lw + row * 36 + (l & 7) * 4);
                    *(us4*)(C + (m0w + row) * (long)N + n0w + jj * 32 + (l & 7) * 4) = vv;
                }
                WAITL0();
            }
        }
    }
}

// ---------------- causal flash attention v2 ----------
__global__ __launch_bounds__(512, 4) void attn_kernel(
    const ushort_t* __restrict__ qkv, ushort_t* __restrict__ o)
{
    __shared__ __align__(16) ushort_t lK[2 * 64 * 128];
    __shared__ __align__(16) ushort_t lVT[128 * 72];
    __shared__ __align__(16) ushort_t lP[8 * 16 * 64];

    const int t = threadIdx.x, w = t >> 6, l = t & 63;
    const int bx = blockIdx.x;
    const int qblk = (bx & 1) ? (15 - (bx >> 1)) : (bx >> 1);
    const int bh = blockIdx.y;
    const int b = bh >> 4, h = bh & 15;
    const int q0 = qblk * 128 + w * 16;
    const long base = (long)b * 2048 * 6144 + (long)h * 128;
    char* lKc = (char*)lK;

    const ushort_t* qrow = qkv + base + (long)(q0 + (l & 15)) * 6144;
    bf16x8 qf[4];
#pragma unroll
    for (int hb = 0; hb < 4; ++hb)
        qf[hb] = *(const bf16x8*)(qrow + hb * 32 + (l >> 4) * 8);

    f32x4 accO[8];
    f32x4 zf = {0.f, 0.f, 0.f, 0.f};
#pragma unroll
    for (int i = 0; i < 8; ++i) accO[i] = zf;
    float m_r[4] = {-1e30f, -1e30f, -1e30f, -1e30f};
    float l_r[4] = {0.f, 0.f, 0.f, 0.f};

    const int nt = (qblk * 128 + 128) >> 6;
    const float scale = 0.08838834764831845f;
    const long TILE_ADV = 64L * 6144 * 2;

    const int kvp = t & 31;
    const int d0 = (t >> 5) * 8;
    us8 va, vb;

    const char* kptr[2];
#pragma unroll
    for (int i = 0; i < 2; ++i) {
        int c = w * 2 + i;
        int row = c * 4 + (l >> 4);
        int src = ((l & 15) * 16) ^ ((row & 7) << 4);
        kptr[i] = (const char*)(qkv + base + 2048 + (long)row * 6144) + src;
    }
    const char* vptr = (const char*)(qkv + base + 4096 + (long)(kvp * 2) * 6144 + d0);

    auto stageK = [&](int buf) {
#pragma unroll
        for (int i = 0; i < 2; ++i) {
            gload16(kptr[i], lKc + buf * 16384 + (w * 2 + i) * 1024);
            kptr[i] += TILE_ADV;
        }
    };
    auto loadV = [&]() {
        va = *(const us8*)vptr;
        vb = *(const us8*)(vptr + 6144 * 2);
        vptr += TILE_ADV;
    };
    auto writeVT = [&]() {
#pragma unroll
        for (int j = 0; j < 8; ++j) {
            unsigned pk = (unsigned)va[j] | ((unsigned)vb[j] << 16);
            *(unsigned*)(lVT + (d0 + j) * 72 + kvp * 2) = pk;
        }
    };

    stageK(0);
    loadV();
    WAITV(0);
    writeVT();
    __syncthreads();

    for (int t0 = 0; t0 < nt; ++t0) {
        const int cur = t0 & 1;
        const bool more = (t0 + 1 < nt);
        if (more) { stageK(cur ^ 1); loadV(); }

        const int kv0 = t0 * 64;
        if (kv0 <= q0 + 15) {
            f32x4 sc[4];
#pragma unroll
            for (int kvs = 0; kvs < 4; ++kvs) {
                sc[kvs] = zf;
                int row = kvs * 16 + (l & 15);
#pragma unroll
                for (int hb = 0; hb < 4; ++hb) {
                    int cb = (hb * 64 + (l >> 4) * 16) ^ ((row & 7) << 4);
                    bf16x8 kf = *(const bf16x8*)(lKc + cur * 16384 + row * 256 + cb);
                    sc[kvs] = __builtin_amdgcn_mfma_f32_16x16x32_bf16(qf[hb], kf, sc[kvs], 0, 0, 0);
                }
            }
#pragma unroll
            for (int r = 0; r < 4; ++r) {
                int qg = q0 + (l >> 4) * 4 + r;
                float s[4];
#pragma unroll
                for (int kvs = 0; kvs < 4; ++kvs) {
                    s[kvs] = sc[kvs][r] * scale;
                    if (kv0 + kvs * 16 + (l & 15) > qg) s[kvs] = -1e30f;
                }
                float pm = fmaxf(fmaxf(s[0], s[1]), fmaxf(s[2], s[3]));
                pm = fmaxf(pm, __shfl_xor(pm, 1));
                pm = fmaxf(pm, __shfl_xor(pm, 2));
                pm = fmaxf(pm, __shfl_xor(pm, 4));
                pm = fmaxf(pm, __shfl_xor(pm, 8));
                float mn = fmaxf(m_r[r], pm);
                float p[4], ps = 0.f;
#pragma unroll
                for (int kvs = 0; kvs < 4; ++kvs) { p[kvs] = __expf(s[kvs] - mn); ps += p[kvs]; }
                ps += __shfl_xor(ps, 1);
                ps += __shfl_xor(ps, 2);
                ps += __shfl_xor(ps, 4);
                ps += __shfl_xor(ps, 8);
                float alpha = __expf(m_r[r] - mn);
                l_r[r] = l_r[r] * alpha + ps;
                m_r[r] = mn;
#pragma unroll
                for (int tt = 0; tt < 8; ++tt) accO[tt][r] *= alpha;
                int qloc = (l >> 4) * 4 + r;
#pragma unroll
                for (int kvs = 0; kvs < 4; ++kvs)
                    lP[w * 1024 + qloc * 64 + kvs * 16 + (l & 15)] = f2bf(p[kvs]);
            }
            WAITL0();
#pragma unroll
            for (int ks = 0; ks < 2; ++ks) {
                bf16x8 pf = *(const bf16x8*)(lP + w * 1024 + (l & 15) * 64 + ks * 32 + (l >> 4) * 8);
#pragma unroll
                for (int tt = 0; tt < 8; ++tt) {
                    bf16x8 vf = *(const bf16x8*)(lVT + (tt * 16 + (l & 15)) * 72 + ks * 32 + (l >> 4) * 8);
                    accO[tt] = __builtin_amdgcn_mfma_f32_16x16x32_bf16(pf, vf, accO[tt], 0, 0, 0);
                }
            }
        }

        WAITV(0);
        __syncthreads();
        if (more) { writeVT(); __syncthreads(); }
    }

    const long obase = (long)b * 2048 * 2048 + (long)h * 128;
#pragma unroll
    for (int r = 0; r < 4; ++r) {
        float inv = 1.f / l_r[r];
        long orow = obase + (long)(q0 + (l >> 4) * 4 + r) * 2048;
#pragma unroll
        for (int tt = 0; tt < 8; ++tt)
            o[orow + tt * 16 + (l & 15)] = f2bf(accO[tt][r] * inv);
    }
}

// ---------------- fused residual + LayerNorm (f32) ----------------
__global__ __launch_bounds__(256) void ln_kernel(
    const float* xres, const ushort_t* __restrict__ addb,
    const float* __restrict__ g, const float* __restrict__ bb,
    float* outf, ushort_t* __restrict__ outb)
{
    __shared__ float rs[4], rss[4];
    const int row = blockIdx.x, t = threadIdx.x;
    const float* xp = xres + (long)row * 2048 + t * 8;
    const ushort_t* ap = addb + (long)row * 2048 + t * 8;
    float4 a = *(const float4*)xp;
    float4 c = *(const float4*)(xp + 4);
    us8 ad = *(const us8*)ap;
    float v[8];
    v[0] = a.x + bf2f(ad[0]); v[1] = a.y + bf2f(ad[1]);
    v[2] = a.z + bf2f(ad[2]); v[3] = a.w + bf2f(ad[3]);
    v[4] = c.x + bf2f(ad[4]); v[5] = c.y + bf2f(ad[5]);
    v[6] = c.z + bf2f(ad[6]); v[7] = c.w + bf2f(ad[7]);
    float s = 0.f, ss = 0.f;
#pragma unroll
    for (int j = 0; j < 8; ++j) { s += v[j]; ss += v[j] * v[j]; }
#pragma unroll
    for (int off = 32; off > 0; off >>= 1) {
        s += __shfl_down(s, off);
        ss += __shfl_down(ss, off);
    }
    if ((t & 63) == 0) { rs[t >> 6] = s; rss[t >> 6] = ss; }
    __syncthreads();
    float S = rs[0] + rs[1] + rs[2] + rs[3];
    float SS = rss[0] + rss[1] + rss[2] + rss[3];
    float mean = S * (1.f / 2048.f);
    float var = SS * (1.f / 2048.f) - mean * mean;
    float rstd = rsqrtf(var + 1e-8f);
    float of[8];
#pragma unroll
    for (int j = 0; j < 8; ++j) {
        int col = t * 8 + j;
        of[j] = (v[j] - mean) * rstd * g[col] + bb[col];
    }
    float4 o1 = {of[0], of[1], of[2], of[3]};
    float4 o2 = {of[4], of[5], of[6], of[7]};
    float* op = outf + (long)row * 2048 + t * 8;
    *(float4*)op = o1;
    *(float4*)(op + 4) = o2;
    if (outb) {
        us8 ob;
#pragma unroll
        for (int j = 0; j < 8; ++j) ob[j] = f2bf(of[j]);
        *(us8*)(outb + (long)row * 2048 + t * 8) = ob;
    }
}

extern "C" void kernel_launch(void* const* d_in, const int* in_sizes, int n_in,
                              void* d_out, int out_size, void* d_ws, size_t ws_size,
                              hipStream_t stream)
{
    const float* x  = (const float*)d_in[0];
    const float* wq = (const float*)d_in[1];
    const float* bq = (const float*)d_in[2];
    const float* wk = (const float*)d_in[3];
    const float* bk = (const float*)d_in[4];
    const float* wv = (const float*)d_in[5];
    const float* bv = (const float*)d_in[6];
    const float* wo = (const float*)d_in[7];
    const float* bo = (const float*)d_in[8];
    const float* g1 = (const float*)d_in[9];
    const float* b1 = (const float*)d_in[10];
    const float* wu = (const float*)d_in[11];
    const float* bu = (const float*)d_in[12];
    const float* wd = (const float*)d_in[13];
    const float* bd = (const float*)d_in[14];
    const float* g2 = (const float*)d_in[15];
    const float* b2 = (const float*)d_in[16];
    (void)in_sizes; (void)n_in; (void)out_size;

    const size_t MB = 1ull << 20;
    char* wsp = (char*)d_ws;
    char*  slotA = wsp;                 // 32MB: transposed weights
    char*  slotB = wsp + 32 * MB;       // 16MB: xb -> ab -> x1b -> db
    char*  slotC = wsp + 48 * MB;       // 64MB: qkvb -> pb -> hb
    float* bqkv  = (float*)(wsp + 112 * MB);
    const size_t need = 112 * MB + 32768;
    if (ws_size < need) {
        fill_kernel<<<(8388608 + 255) / 256, 256, 0, stream>>>((float*)d_out, 8388608L, 1e6f);
        return;
    }

    ushort_t* xb   = (ushort_t*)slotB;
    ushort_t* wT   = (ushort_t*)slotA;
    ushort_t* qkvb = (ushort_t*)slotC;
    ushort_t* ab   = (ushort_t*)slotB;
    ushort_t* pb   = (ushort_t*)slotC;
    float*    x1f  = (float*)d_out;
    ushort_t* x1b  = (ushort_t*)slotB;
    ushort_t* hb   = (ushort_t*)slotC;
    ushort_t* db   = (ushort_t*)slotB;

    // 1) cast x -> bf16
    cast_bf16_kernel<<<8192, 256, 0, stream>>>(x, xb, 8388608L);
    // 2) merged transpose wq|wk|wv -> wT, pack biases
    transpose3_bf16_kernel<<<dim3(64, 64, 3), 256, 0, stream>>>(wq, wk, wv, wT);
    hipMemcpyAsync(bqkv,        bq, 2048 * sizeof(float), hipMemcpyDeviceToDevice, stream);
    hipMemcpyAsync(bqkv + 2048, bk, 2048 * sizeof(float), hipMemcpyDeviceToDevice, stream);
    hipMemcpyAsync(bqkv + 4096, bv, 2048 * sizeof(float), hipMemcpyDeviceToDevice, stream);
    // 3) fused QKV projection: 256^2 8-phase, grid 16x24
    gemm8p_kernel<<<dim3(16, 24), 512, 0, stream>>>(xb, wT, bqkv, qkvb, 4096, 6144, 2048, 0);
    // 4) causal attention
    attn_kernel<<<dim3(16, 32), 512, 0, stream>>>(qkvb, ab);
    // 5) transpose wo -> wT
    transpose_bf16_kernel<<<dim3(64, 64), 256, 0, stream>>>(wo, wT, 2048, 2048);
    // 6) output projection (N=2048: BK=128 128^2)
    gemm_bt128_kernel<<<dim3(32, 16), 256, 0, stream>>>(ab, wT, bo, pb, 4096, 2048, 2048, 0);
    // 7) residual + LN1
    ln_kernel<<<4096, 256, 0, stream>>>(x, pb, g1, b1, x1f, x1b);
    // 8) transpose wu -> wT
    transpose_bf16_kernel<<<dim3(256, 64), 256, 0, stream>>>(wu, wT, 2048, 8192);
    // 9) FFN up + exact GELU: 256^2 8-phase, grid 16x32
    gemm8p_kernel<<<dim3(16, 32), 512, 0, stream>>>(x1b, wT, bu, hb, 4096, 8192, 2048, 1);
    // 10) transpose wd -> wT
    transpose_bf16_kernel<<<dim3(64, 256), 256, 0, stream>>>(wd, wT, 8192, 2048);
    // 11) FFN down (K=8192: BK=128 128^2)
    gemm_bt128_kernel<<<dim3(32, 16), 256, 0, stream>>>(hb, wT, bd, db, 4096, 2048, 8192, 0);
    // 12) residual + LN2
    ln_kernel<<<4096, 256, 0, stream>>>(x1f, db, g2, b2, (float*)d_out, nullptr);
}

// Round 14
// 699.648 us; speedup vs baseline: 1.0238x; 1.0238x over previous
//
#include <hip/hip_runtime.h>
#include <hip/hip_bf16.h>
#include <math.h>

#define DEV __device__ __forceinline__

typedef __bf16 bf16x8 __attribute__((ext_vector_type(8)));
typedef float f32x4 __attribute__((ext_vector_type(4)));
typedef unsigned short ushort_t;
typedef ushort_t us8 __attribute__((ext_vector_type(8)));
typedef ushort_t us4 __attribute__((ext_vector_type(4)));

DEV float bf2f(ushort_t u) {
    unsigned v = ((unsigned)u) << 16;
    float f; __builtin_memcpy(&f, &v, 4); return f;
}
// native HW convert (v_cvt bf16, RNE)
DEV ushort_t f2bf(float f) {
    __bf16 h = (__bf16)f;
    ushort_t u; __builtin_memcpy(&u, &h, 2); return u;
}

DEV void gload16(const void* g, void* l) {
    __builtin_amdgcn_global_load_lds(
        (const __attribute__((address_space(1))) void*)g,
        (__attribute__((address_space(3))) void*)l, 16, 0, 0);
}

// ---------------- sentinel fill (ws too small diagnostic) ----------------
__global__ __launch_bounds__(256) void fill_kernel(float* out, long n, float v) {
    long i = (long)blockIdx.x * blockDim.x + threadIdx.x;
    if (i < n) out[i] = v;
}

// ---------------- cast f32 -> bf16 ----------------
__global__ __launch_bounds__(256) void cast_bf16_kernel(
    const float* __restrict__ in, ushort_t* __restrict__ out, long n)
{
    long i = ((long)blockIdx.x * blockDim.x + threadIdx.x) * 4;
    if (i >= n) return;
    float4 v = *(const float4*)(in + i);
    us4 o = { f2bf(v.x), f2bf(v.y), f2bf(v.z), f2bf(v.w) };
    *(us4*)(out + i) = o;
}

// ---------------- transpose + cast: in[R][C] f32 -> out[C][R] bf16 ----------------
__global__ __launch_bounds__(256) void transpose_bf16_kernel(
    const float* __restrict__ in, ushort_t* __restrict__ out, int R, int C)
{
    __shared__ float tile[32][33];
    int c0 = blockIdx.x * 32, r0 = blockIdx.y * 32;
    int tx = threadIdx.x & 31, ty = threadIdx.x >> 5;
#pragma unroll
    for (int j = 0; j < 4; ++j) {
        int r = ty + j * 8;
        tile[r][tx] = in[(long)(r0 + r) * C + (c0 + tx)];
    }
    __syncthreads();
#pragma unroll
    for (int j = 0; j < 4; ++j) {
        int r = ty + j * 8;
        out[(long)(c0 + r) * R + (r0 + tx)] = f2bf(tile[tx][r]);
    }
}

// ---------------- merged 3-way transpose (wq|wk|wv 2048x2048 each) ----------------
__global__ __launch_bounds__(256) void transpose3_bf16_kernel(
    const float* __restrict__ w0, const float* __restrict__ w1,
    const float* __restrict__ w2, ushort_t* __restrict__ out)
{
    __shared__ float tile[32][33];
    const float* in = (blockIdx.z == 0) ? w0 : (blockIdx.z == 1) ? w1 : w2;
    ushort_t* o = out + (size_t)blockIdx.z * 2048 * 2048;
    int c0 = blockIdx.x * 32, r0 = blockIdx.y * 32;
    int tx = threadIdx.x & 31, ty = threadIdx.x >> 5;
#pragma unroll
    for (int j = 0; j < 4; ++j) {
        int r = ty + j * 8;
        tile[r][tx] = in[(long)(r0 + r) * 2048 + (c0 + tx)];
    }
    __syncthreads();
#pragma unroll
    for (int j = 0; j < 4; ++j) {
        int r = ty + j * 8;
        o[(long)(c0 + r) * 2048 + (r0 + tx)] = f2bf(tile[tx][r]);
    }
}

// Coalesced GEMM epilogue: per-wave private LDS transpose (64x32 bf16, 72B row
// stride), then 8-lane groups store full 64B sectors (us4 per lane).
DEV void epilogue_store(f32x4 (&acc)[4][4], const float* bias, ushort_t* C,
                        long m0, long n0, int N, int act, int wr, int wc, int l,
                        char* lwb)
{
    ushort_t* lw = (ushort_t*)lwb;
#pragma unroll
    for (int jj = 0; jj < 2; ++jj) {
#pragma unroll
        for (int jh = 0; jh < 2; ++jh) {
            int j = jj * 2 + jh;
            int col = (int)n0 + wc * 64 + j * 16 + (l & 15);
            float bv = bias[col];
#pragma unroll
            for (int i = 0; i < 4; ++i) {
#pragma unroll
                for (int r = 0; r < 4; ++r) {
                    float v2 = acc[i][j][r] + bv;
                    if (act == 1) v2 = 0.5f * v2 * (1.f + erff(v2 * 0.70710678118654752440f));
                    lw[(i * 16 + (l >> 4) * 4 + r) * 36 + jh * 16 + (l & 15)] = f2bf(v2);
                }
            }
        }
        asm volatile("s_waitcnt lgkmcnt(0)" ::: "memory");
#pragma unroll
        for (int p = 0; p < 8; ++p) {
            int row = p * 8 + (l >> 3);
            us4 vv = *(const us4*)(lw + row * 36 + (l & 7) * 4);
            *(us4*)(C + (m0 + wr * 64 + row) * (long)N + n0 + wc * 64 + jj * 32 + (l & 7) * 4) = vv;
        }
        asm volatile("s_waitcnt lgkmcnt(0)" ::: "memory");
    }
}

// ---------------- GEMM 128x128, BK=64 (m97 structure + ptr strength-reduction) ---
__global__ __launch_bounds__(256) void gemm_bt_kernel(
    const ushort_t* __restrict__ A, const ushort_t* __restrict__ Bt,
    const float* __restrict__ bias, ushort_t* __restrict__ C,
    int M, int N, int K, int act)
{
    __shared__ __align__(16) ushort_t lA[128 * 64];
    __shared__ __align__(16) ushort_t lB[128 * 64];
    const int t = threadIdx.x;
    const int w = t >> 6, l = t & 63;
    const int wr = w >> 1, wc = w & 1;
    const long m0 = (long)blockIdx.x * 128;
    const long n0 = (long)blockIdx.y * 128;

    const int sr = l >> 3;
    const int scol = (l & 7) * 16;

    f32x4 acc[4][4];
    f32x4 zf = {0.f, 0.f, 0.f, 0.f};
#pragma unroll
    for (int i = 0; i < 4; ++i)
#pragma unroll
        for (int j = 0; j < 4; ++j) acc[i][j] = zf;

    char* lAc = (char*)lA;
    char* lBc = (char*)lB;

    // strength-reduced staging pointers: recompute nothing in-loop, just += 128B
    const char* aptr[4];
    const char* bptr[4];
#pragma unroll
    for (int c = 0; c < 4; ++c) {
        int row = (w * 4 + c) * 8 + sr;
        int src = scol ^ ((row & 7) << 4);
        aptr[c] = (const char*)(A + (m0 + row) * (long)K) + src;
        bptr[c] = (const char*)(Bt + (n0 + row) * (long)K) + src;
    }

    for (int k0 = 0; k0 < K; k0 += 64) {
        __syncthreads();
#pragma unroll
        for (int c = 0; c < 4; ++c) {
            gload16(aptr[c], lAc + (w * 4 + c) * 1024);
            gload16(bptr[c], lBc + (w * 4 + c) * 1024);
            aptr[c] += 128;
            bptr[c] += 128;
        }
        __syncthreads();
#pragma unroll
        for (int ks = 0; ks < 2; ++ks) {
            bf16x8 af[4], bfr[4];
#pragma unroll
            for (int i = 0; i < 4; ++i) {
                int row = wr * 64 + i * 16 + (l & 15);
                int cb = (ks * 64 + (l >> 4) * 16) ^ ((row & 7) << 4);
                af[i] = *(const bf16x8*)(lAc + row * 128 + cb);
            }
#pragma unroll
            for (int j = 0; j < 4; ++j) {
                int row = wc * 64 + j * 16 + (l & 15);
                int cb = (ks * 64 + (l >> 4) * 16) ^ ((row & 7) << 4);
                bfr[j] = *(const bf16x8*)(lBc + row * 128 + cb);
            }
#pragma unroll
            for (int i = 0; i < 4; ++i)
#pragma unroll
                for (int j = 0; j < 4; ++j)
                    acc[i][j] = __builtin_amdgcn_mfma_f32_16x16x32_bf16(af[i], bfr[j], acc[i][j], 0, 0, 0);
        }
    }

    __syncthreads();   // all LDS tile reads done before epilogue reuses lA/lB
    epilogue_store(acc, bias, C, m0, n0, N, act, wr, wc, l,
                   (w < 2 ? lAc : lBc) + (w & 1) * 4608);
}

// ---------------- GEMM 128x128, BK=128 (+ ptr strength-reduction) ----------
__global__ __launch_bounds__(256) void gemm_bt128_kernel(
    const ushort_t* __restrict__ A, const ushort_t* __restrict__ Bt,
    const float* __restrict__ bias, ushort_t* __restrict__ C,
    int M, int N, int K, int act)
{
    __shared__ __align__(16) ushort_t lA[128 * 128];   // 32KB
    __shared__ __align__(16) ushort_t lB[128 * 128];   // 32KB
    const int t = threadIdx.x;
    const int w = t >> 6, l = t & 63;
    const int wr = w >> 1, wc = w & 1;
    const long m0 = (long)blockIdx.x * 128;
    const long n0 = (long)blockIdx.y * 128;

    const int srow = t >> 4;
    const int ssrc = ((t & 15) * 16) ^ ((srow & 7) << 4);

    f32x4 acc[4][4];
    f32x4 zf = {0.f, 0.f, 0.f, 0.f};
#pragma unroll
    for (int i = 0; i < 4; ++i)
#pragma unroll
        for (int j = 0; j < 4; ++j) acc[i][j] = zf;

    char* lAc = (char*)lA;
    char* lBc = (char*)lB;

    const char* aptr[8];
    const char* bptr[8];
#pragma unroll
    for (int r = 0; r < 8; ++r) {
        int row = r * 16 + srow;
        aptr[r] = (const char*)(A + (m0 + row) * (long)K) + ssrc;
        bptr[r] = (const char*)(Bt + (n0 + row) * (long)K) + ssrc;
    }

    for (int k0 = 0; k0 < K; k0 += 128) {
        __syncthreads();
#pragma unroll
        for (int r = 0; r < 8; ++r) {
            gload16(aptr[r], lAc + r * 4096 + t * 16);
            gload16(bptr[r], lBc + r * 4096 + t * 16);
            aptr[r] += 256;
            bptr[r] += 256;
        }
        __syncthreads();
#pragma unroll
        for (int ks = 0; ks < 4; ++ks) {
            bf16x8 af[4], bfr[4];
#pragma unroll
            for (int i = 0; i < 4; ++i) {
                int row = wr * 64 + i * 16 + (l & 15);
                int cb = (ks * 64 + (l >> 4) * 16) ^ ((row & 7) << 4);
                af[i] = *(const bf16x8*)(lAc + row * 256 + cb);
            }
#pragma unroll
            for (int j = 0; j < 4; ++j) {
                int row = wc * 64 + j * 16 + (l & 15);
                int cb = (ks * 64 + (l >> 4) * 16) ^ ((row & 7) << 4);
                bfr[j] = *(const bf16x8*)(lBc + row * 256 + cb);
            }
#pragma unroll
            for (int i = 0; i < 4; ++i)
#pragma unroll
                for (int j = 0; j < 4; ++j)
                    acc[i][j] = __builtin_amdgcn_mfma_f32_16x16x32_bf16(af[i], bfr[j], acc[i][j], 0, 0, 0);
        }
    }

    __syncthreads();
    epilogue_store(acc, bias, C, m0, n0, N, act, wr, wc, l,
                   (w < 2 ? lAc : lBc) + (w & 1) * 4608);
}

// ---------------- causal flash attention v2 (+ ptr strength-reduction) ----------
__global__ __launch_bounds__(512, 4) void attn_kernel(
    const ushort_t* __restrict__ qkv, ushort_t* __restrict__ o)
{
    __shared__ __align__(16) ushort_t lK[2 * 64 * 128];   // 32KB, 2 bufs, swizzled
    __shared__ __align__(16) ushort_t lVT[128 * 72];      // 18KB, V^T padded to 72
    __shared__ __align__(16) ushort_t lP[8 * 16 * 64];    // 16KB, per-wave P

    const int t = threadIdx.x, w = t >> 6, l = t & 63;
    const int bx = blockIdx.x;
    const int qblk = (bx & 1) ? (15 - (bx >> 1)) : (bx >> 1);
    const int bh = blockIdx.y;
    const int b = bh >> 4, h = bh & 15;
    const int q0 = qblk * 128 + w * 16;
    const long base = (long)b * 2048 * 6144 + (long)h * 128;
    char* lKc = (char*)lK;

    const ushort_t* qrow = qkv + base + (long)(q0 + (l & 15)) * 6144;
    bf16x8 qf[4];
#pragma unroll
    for (int hb = 0; hb < 4; ++hb)
        qf[hb] = *(const bf16x8*)(qrow + hb * 32 + (l >> 4) * 8);

    f32x4 accO[8];
    f32x4 zf = {0.f, 0.f, 0.f, 0.f};
#pragma unroll
    for (int i = 0; i < 8; ++i) accO[i] = zf;
    float m_r[4] = {-1e30f, -1e30f, -1e30f, -1e30f};
    float l_r[4] = {0.f, 0.f, 0.f, 0.f};

    const int nt = (qblk * 128 + 128) >> 6;
    const float scale = 0.08838834764831845f;
    const long TILE_ADV = 64L * 6144 * 2;   // bytes per kv tile

    const int kvp = t & 31;
    const int d0 = (t >> 5) * 8;
    us8 va, vb;

    // strength-reduced staging pointers
    const char* kptr[2];
#pragma unroll
    for (int i = 0; i < 2; ++i) {
        int c = w * 2 + i;
        int row = c * 4 + (l >> 4);
        int src = ((l & 15) * 16) ^ ((row & 7) << 4);
        kptr[i] = (const char*)(qkv + base + 2048 + (long)row * 6144) + src;
    }
    const char* vptr = (const char*)(qkv + base + 4096 + (long)(kvp * 2) * 6144 + d0);

    auto stageK = [&](int buf) {
#pragma unroll
        for (int i = 0; i < 2; ++i) {
            gload16(kptr[i], lKc + buf * 16384 + (w * 2 + i) * 1024);
            kptr[i] += TILE_ADV;
        }
    };
    auto loadV = [&]() {
        va = *(const us8*)vptr;
        vb = *(const us8*)(vptr + 6144 * 2);
        vptr += TILE_ADV;
    };
    auto writeVT = [&]() {
#pragma unroll
        for (int j = 0; j < 8; ++j) {
            unsigned pk = (unsigned)va[j] | ((unsigned)vb[j] << 16);
            *(unsigned*)(lVT + (d0 + j) * 72 + kvp * 2) = pk;
        }
    };

    stageK(0);
    loadV();
    asm volatile("s_waitcnt vmcnt(0)" ::: "memory");
    writeVT();
    __syncthreads();

    for (int t0 = 0; t0 < nt; ++t0) {
        const int cur = t0 & 1;
        const bool more = (t0 + 1 < nt);
        if (more) { stageK(cur ^ 1); loadV(); }

        const int kv0 = t0 * 64;
        if (kv0 <= q0 + 15) {
            f32x4 sc[4];
#pragma unroll
            for (int kvs = 0; kvs < 4; ++kvs) {
                sc[kvs] = zf;
                int row = kvs * 16 + (l & 15);
#pragma unroll
                for (int hb = 0; hb < 4; ++hb) {
                    int cb = (hb * 64 + (l >> 4) * 16) ^ ((row & 7) << 4);
                    bf16x8 kf = *(const bf16x8*)(lKc + cur * 16384 + row * 256 + cb);
                    sc[kvs] = __builtin_amdgcn_mfma_f32_16x16x32_bf16(qf[hb], kf, sc[kvs], 0, 0, 0);
                }
            }
#pragma unroll
            for (int r = 0; r < 4; ++r) {
                int qg = q0 + (l >> 4) * 4 + r;
                float s[4];
#pragma unroll
                for (int kvs = 0; kvs < 4; ++kvs) {
                    s[kvs] = sc[kvs][r] * scale;
                    if (kv0 + kvs * 16 + (l & 15) > qg) s[kvs] = -1e30f;
                }
                float pm = fmaxf(fmaxf(s[0], s[1]), fmaxf(s[2], s[3]));
                pm = fmaxf(pm, __shfl_xor(pm, 1));
                pm = fmaxf(pm, __shfl_xor(pm, 2));
                pm = fmaxf(pm, __shfl_xor(pm, 4));
                pm = fmaxf(pm, __shfl_xor(pm, 8));
                float mn = fmaxf(m_r[r], pm);
                float p[4], ps = 0.f;
#pragma unroll
                for (int kvs = 0; kvs < 4; ++kvs) { p[kvs] = __expf(s[kvs] - mn); ps += p[kvs]; }
                ps += __shfl_xor(ps, 1);
                ps += __shfl_xor(ps, 2);
                ps += __shfl_xor(ps, 4);
                ps += __shfl_xor(ps, 8);
                float alpha = __expf(m_r[r] - mn);
                l_r[r] = l_r[r] * alpha + ps;
                m_r[r] = mn;
#pragma unroll
                for (int tt = 0; tt < 8; ++tt) accO[tt][r] *= alpha;
                int qloc = (l >> 4) * 4 + r;
#pragma unroll
                for (int kvs = 0; kvs < 4; ++kvs)
                    lP[w * 1024 + qloc * 64 + kvs * 16 + (l & 15)] = f2bf(p[kvs]);
            }
            asm volatile("s_waitcnt lgkmcnt(0)" ::: "memory");
#pragma unroll
            for (int ks = 0; ks < 2; ++ks) {
                bf16x8 pf = *(const bf16x8*)(lP + w * 1024 + (l & 15) * 64 + ks * 32 + (l >> 4) * 8);
#pragma unroll
                for (int tt = 0; tt < 8; ++tt) {
                    bf16x8 vf = *(const bf16x8*)(lVT + (tt * 16 + (l & 15)) * 72 + ks * 32 + (l >> 4) * 8);
                    accO[tt] = __builtin_amdgcn_mfma_f32_16x16x32_bf16(pf, vf, accO[tt], 0, 0, 0);
                }
            }
        }

        asm volatile("s_waitcnt vmcnt(0)" ::: "memory");
        __syncthreads();
        if (more) { writeVT(); __syncthreads(); }
    }

    const long obase = (long)b * 2048 * 2048 + (long)h * 128;
#pragma unroll
    for (int r = 0; r < 4; ++r) {
        float inv = 1.f / l_r[r];
        long orow = obase + (long)(q0 + (l >> 4) * 4 + r) * 2048;
#pragma unroll
        for (int tt = 0; tt < 8; ++tt)
            o[orow + tt * 16 + (l & 15)] = f2bf(accO[tt][r] * inv);
    }
}

// ---------------- fused residual + LayerNorm (f32) ----------------
__global__ __launch_bounds__(256) void ln_kernel(
    const float* xres, const ushort_t* __restrict__ addb,
    const float* __restrict__ g, const float* __restrict__ bb,
    float* outf, ushort_t* __restrict__ outb)
{
    __shared__ float rs[4], rss[4];
    const int row = blockIdx.x, t = threadIdx.x;
    const float* xp = xres + (long)row * 2048 + t * 8;
    const ushort_t* ap = addb + (long)row * 2048 + t * 8;
    float4 a = *(const float4*)xp;
    float4 c = *(const float4*)(xp + 4);
    us8 ad = *(const us8*)ap;
    float v[8];
    v[0] = a.x + bf2f(ad[0]); v[1] = a.y + bf2f(ad[1]);
    v[2] = a.z + bf2f(ad[2]); v[3] = a.w + bf2f(ad[3]);
    v[4] = c.x + bf2f(ad[4]); v[5] = c.y + bf2f(ad[5]);
    v[6] = c.z + bf2f(ad[6]); v[7] = c.w + bf2f(ad[7]);
    float s = 0.f, ss = 0.f;
#pragma unroll
    for (int j = 0; j < 8; ++j) { s += v[j]; ss += v[j] * v[j]; }
#pragma unroll
    for (int off = 32; off > 0; off >>= 1) {
        s += __shfl_down(s, off);
        ss += __shfl_down(ss, off);
    }
    if ((t & 63) == 0) { rs[t >> 6] = s; rss[t >> 6] = ss; }
    __syncthreads();
    float S = rs[0] + rs[1] + rs[2] + rs[3];
    float SS = rss[0] + rss[1] + rss[2] + rss[3];
    float mean = S * (1.f / 2048.f);
    float var = SS * (1.f / 2048.f) - mean * mean;
    float rstd = rsqrtf(var + 1e-8f);
    float of[8];
#pragma unroll
    for (int j = 0; j < 8; ++j) {
        int col = t * 8 + j;
        of[j] = (v[j] - mean) * rstd * g[col] + bb[col];
    }
    float4 o1 = {of[0], of[1], of[2], of[3]};
    float4 o2 = {of[4], of[5], of[6], of[7]};
    float* op = outf + (long)row * 2048 + t * 8;
    *(float4*)op = o1;
    *(float4*)(op + 4) = o2;
    if (outb) {
        us8 ob;
#pragma unroll
        for (int j = 0; j < 8; ++j) ob[j] = f2bf(of[j]);
        *(us8*)(outb + (long)row * 2048 + t * 8) = ob;
    }
}

extern "C" void kernel_launch(void* const* d_in, const int* in_sizes, int n_in,
                              void* d_out, int out_size, void* d_ws, size_t ws_size,
                              hipStream_t stream)
{
    const float* x  = (const float*)d_in[0];
    const float* wq = (const float*)d_in[1];
    const float* bq = (const float*)d_in[2];
    const float* wk = (const float*)d_in[3];
    const float* bk = (const float*)d_in[4];
    const float* wv = (const float*)d_in[5];
    const float* bv = (const float*)d_in[6];
    const float* wo = (const float*)d_in[7];
    const float* bo = (const float*)d_in[8];
    const float* g1 = (const float*)d_in[9];
    const float* b1 = (const float*)d_in[10];
    const float* wu = (const float*)d_in[11];
    const float* bu = (const float*)d_in[12];
    const float* wd = (const float*)d_in[13];
    const float* bd = (const float*)d_in[14];
    const float* g2 = (const float*)d_in[15];
    const float* b2 = (const float*)d_in[16];
    (void)in_sizes; (void)n_in; (void)out_size;

    // ---- slot-based workspace (sequential lifetime reuse), total 112MB+32KB ----
    const size_t MB = 1ull << 20;
    char* wsp = (char*)d_ws;
    char*  slotA = wsp;                 // 32MB: qkvT(24) -> woT(8) -> wuT(32) -> wdT(32)
    char*  slotB = wsp + 32 * MB;       // 16MB: xb -> ab -> x1b -> db
    char*  slotC = wsp + 48 * MB;       // 64MB: qkvb(48) -> pb(16) -> hb(64)
    float* bqkv  = (float*)(wsp + 112 * MB); // 24KB
    const size_t need = 112 * MB + 32768;
    if (ws_size < need) {
        fill_kernel<<<(8388608 + 255) / 256, 256, 0, stream>>>((float*)d_out, 8388608L, 1e6f);
        return;
    }

    ushort_t* xb   = (ushort_t*)slotB;             // [4096][2048] bf16
    ushort_t* wT   = (ushort_t*)slotA;             // current transposed weight
    ushort_t* qkvb = (ushort_t*)slotC;             // [4096][6144]
    ushort_t* ab   = (ushort_t*)slotB;             // [4096][2048]
    ushort_t* pb   = (ushort_t*)slotC;             // [4096][2048]
    float*    x1f  = (float*)d_out;                // [4096][2048] f32 (borrow d_out)
    ushort_t* x1b  = (ushort_t*)slotB;             // [4096][2048]
    ushort_t* hb   = (ushort_t*)slotC;             // [4096][8192]
    ushort_t* db   = (ushort_t*)slotB;             // [4096][2048]

    // 1) cast x -> bf16
    cast_bf16_kernel<<<8192, 256, 0, stream>>>(x, xb, 8388608L);
    // 2) merged transpose wq|wk|wv -> wT (24MB), pack biases
    transpose3_bf16_kernel<<<dim3(64, 64, 3), 256, 0, stream>>>(wq, wk, wv, wT);
    hipMemcpyAsync(bqkv,        bq, 2048 * sizeof(float), hipMemcpyDeviceToDevice, stream);
    hipMemcpyAsync(bqkv + 2048, bk, 2048 * sizeof(float), hipMemcpyDeviceToDevice, stream);
    hipMemcpyAsync(bqkv + 4096, bv, 2048 * sizeof(float), hipMemcpyDeviceToDevice, stream);
    // 3) fused QKV projection: [4096,2048]@[2048,6144] (2D grid, BK=64)
    gemm_bt_kernel<<<dim3(32, 48), 256, 0, stream>>>(xb, wT, bqkv, qkvb, 4096, 6144, 2048, 0);
    // 4) causal attention
    attn_kernel<<<dim3(16, 32), 512, 0, stream>>>(qkvb, ab);
    // 5) transpose wo -> wT
    transpose_bf16_kernel<<<dim3(64, 64), 256, 0, stream>>>(wo, wT, 2048, 2048);
    // 6) output projection (grid-limited: BK=128, 2D grid)
    gemm_bt128_kernel<<<dim3(32, 16), 256, 0, stream>>>(ab, wT, bo, pb, 4096, 2048, 2048, 0);
    // 7) residual + LN1 -> x1f (in d_out) + x1b
    ln_kernel<<<4096, 256, 0, stream>>>(x, pb, g1, b1, x1f, x1b);
    // 8) transpose wu -> wT
    transpose_bf16_kernel<<<dim3(256, 64), 256, 0, stream>>>(wu, wT, 2048, 8192);
    // 9) FFN up + exact GELU (2D grid, BK=64)
    gemm_bt_kernel<<<dim3(32, 64), 256, 0, stream>>>(x1b, wT, bu, hb, 4096, 8192, 2048, 1);
    // 10) transpose wd -> wT
    transpose_bf16_kernel<<<dim3(64, 256), 256, 0, stream>>>(wd, wT, 8192, 2048);
    // 11) FFN down (K=8192, grid-limited: BK=128, 2D grid)
    gemm_bt128_kernel<<<dim3(32, 16), 256, 0, stream>>>(hb, wT, bd, db, 4096, 2048, 8192, 0);
    // 12) residual + LN2 (reads x1f from d_out, writes d_out in place)
    ln_kernel<<<4096, 256, 0, stream>>>(x1f, db, g2, b2, (float*)d_out, nullptr);
}

// Round 15
// 665.775 us; speedup vs baseline: 1.0758x; 1.0509x over previous
//
#include <hip/hip_runtime.h>
#include <hip/hip_bf16.h>
#include <math.h>

#define DEV __device__ __forceinline__

typedef __bf16 bf16x8 __attribute__((ext_vector_type(8)));
typedef float f32x4 __attribute__((ext_vector_type(4)));
typedef unsigned short ushort_t;
typedef ushort_t us8 __attribute__((ext_vector_type(8)));
typedef ushort_t us4 __attribute__((ext_vector_type(4)));

DEV float bf2f(ushort_t u) {
    unsigned v = ((unsigned)u) << 16;
    float f; __builtin_memcpy(&f, &v, 4); return f;
}
// native HW convert (v_cvt bf16, RNE)
DEV ushort_t f2bf(float f) {
    __bf16 h = (__bf16)f;
    ushort_t u; __builtin_memcpy(&u, &h, 2); return u;
}

DEV void gload16(const void* g, void* l) {
    __builtin_amdgcn_global_load_lds(
        (const __attribute__((address_space(1))) void*)g,
        (__attribute__((address_space(3))) void*)l, 16, 0, 0);
}

// ---------------- sentinel fill (ws too small diagnostic) ----------------
__global__ __launch_bounds__(256) void fill_kernel(float* out, long n, float v) {
    long i = (long)blockIdx.x * blockDim.x + threadIdx.x;
    if (i < n) out[i] = v;
}

// ---------------- cast f32 -> bf16 ----------------
__global__ __launch_bounds__(256) void cast_bf16_kernel(
    const float* __restrict__ in, ushort_t* __restrict__ out, long n)
{
    long i = ((long)blockIdx.x * blockDim.x + threadIdx.x) * 4;
    if (i >= n) return;
    float4 v = *(const float4*)(in + i);
    us4 o = { f2bf(v.x), f2bf(v.y), f2bf(v.z), f2bf(v.w) };
    *(us4*)(out + i) = o;
}

// ---------------- transpose + cast: in[R][C] f32 -> out[C][R] bf16 ----------------
__global__ __launch_bounds__(256) void transpose_bf16_kernel(
    const float* __restrict__ in, ushort_t* __restrict__ out, int R, int C)
{
    __shared__ float tile[32][33];
    int c0 = blockIdx.x * 32, r0 = blockIdx.y * 32;
    int tx = threadIdx.x & 31, ty = threadIdx.x >> 5;
#pragma unroll
    for (int j = 0; j < 4; ++j) {
        int r = ty + j * 8;
        tile[r][tx] = in[(long)(r0 + r) * C + (c0 + tx)];
    }
    __syncthreads();
#pragma unroll
    for (int j = 0; j < 4; ++j) {
        int r = ty + j * 8;
        out[(long)(c0 + r) * R + (r0 + tx)] = f2bf(tile[tx][r]);
    }
}

// ---------------- merged 3-way transpose (wq|wk|wv 2048x2048 each) ----------------
__global__ __launch_bounds__(256) void transpose3_bf16_kernel(
    const float* __restrict__ w0, const float* __restrict__ w1,
    const float* __restrict__ w2, ushort_t* __restrict__ out)
{
    __shared__ float tile[32][33];
    const float* in = (blockIdx.z == 0) ? w0 : (blockIdx.z == 1) ? w1 : w2;
    ushort_t* o = out + (size_t)blockIdx.z * 2048 * 2048;
    int c0 = blockIdx.x * 32, r0 = blockIdx.y * 32;
    int tx = threadIdx.x & 31, ty = threadIdx.x >> 5;
#pragma unroll
    for (int j = 0; j < 4; ++j) {
        int r = ty + j * 8;
        tile[r][tx] = in[(long)(r0 + r) * 2048 + (c0 + tx)];
    }
    __syncthreads();
#pragma unroll
    for (int j = 0; j < 4; ++j) {
        int r = ty + j * 8;
        o[(long)(c0 + r) * 2048 + (r0 + tx)] = f2bf(tile[tx][r]);
    }
}

// Coalesced GEMM epilogue: per-wave private LDS transpose (64x32 bf16, 72B row
// stride), then 8-lane groups store full 64B sectors (us4 per lane).
DEV void epilogue_store(f32x4 (&acc)[4][4], const float* bias, ushort_t* C,
                        long m0, long n0, int N, int act, int wr, int wc, int l,
                        char* lwb)
{
    ushort_t* lw = (ushort_t*)lwb;
#pragma unroll
    for (int jj = 0; jj < 2; ++jj) {
#pragma unroll
        for (int jh = 0; jh < 2; ++jh) {
            int j = jj * 2 + jh;
            int col = (int)n0 + wc * 64 + j * 16 + (l & 15);
            float bv = bias[col];
#pragma unroll
            for (int i = 0; i < 4; ++i) {
#pragma unroll
                for (int r = 0; r < 4; ++r) {
                    float v2 = acc[i][j][r] + bv;
                    if (act == 1) v2 = 0.5f * v2 * (1.f + erff(v2 * 0.70710678118654752440f));
                    lw[(i * 16 + (l >> 4) * 4 + r) * 36 + jh * 16 + (l & 15)] = f2bf(v2);
                }
            }
        }
        asm volatile("s_waitcnt lgkmcnt(0)" ::: "memory");
#pragma unroll
        for (int p = 0; p < 8; ++p) {
            int row = p * 8 + (l >> 3);
            us4 vv = *(const us4*)(lw + row * 36 + (l & 7) * 4);
            *(us4*)(C + (m0 + wr * 64 + row) * (long)N + n0 + wc * 64 + jj * 32 + (l & 7) * 4) = vv;
        }
        asm volatile("s_waitcnt lgkmcnt(0)" ::: "memory");
    }
}

// ---------------- GEMM 128x128, BK=64 (m97 structure; occupancy-forced) ---------
// __launch_bounds__(256, 4): cap unified regs at 128/wave -> 4 blocks/CU target
// (was 80 VGPR + 64 AGPR = 144 -> 3 waves/SIMD, Occupancy ~31%).
__global__ __launch_bounds__(256, 4) void gemm_bt_kernel(
    const ushort_t* __restrict__ A, const ushort_t* __restrict__ Bt,
    const float* __restrict__ bias, ushort_t* __restrict__ C,
    int M, int N, int K, int act)
{
    __shared__ __align__(16) ushort_t lA[128 * 64];
    __shared__ __align__(16) ushort_t lB[128 * 64];
    const int t = threadIdx.x;
    const int w = t >> 6, l = t & 63;
    const int wr = w >> 1, wc = w & 1;
    const long m0 = (long)blockIdx.x * 128;
    const long n0 = (long)blockIdx.y * 128;

    const int sr = l >> 3;
    const int scol = (l & 7) * 16;

    f32x4 acc[4][4];
    f32x4 zf = {0.f, 0.f, 0.f, 0.f};
#pragma unroll
    for (int i = 0; i < 4; ++i)
#pragma unroll
        for (int j = 0; j < 4; ++j) acc[i][j] = zf;

    char* lAc = (char*)lA;
    char* lBc = (char*)lB;

    // strength-reduced staging pointers: recompute nothing in-loop, just += 128B
    const char* aptr[4];
    const char* bptr[4];
#pragma unroll
    for (int c = 0; c < 4; ++c) {
        int row = (w * 4 + c) * 8 + sr;
        int src = scol ^ ((row & 7) << 4);
        aptr[c] = (const char*)(A + (m0 + row) * (long)K) + src;
        bptr[c] = (const char*)(Bt + (n0 + row) * (long)K) + src;
    }

    for (int k0 = 0; k0 < K; k0 += 64) {
        __syncthreads();
#pragma unroll
        for (int c = 0; c < 4; ++c) {
            gload16(aptr[c], lAc + (w * 4 + c) * 1024);
            gload16(bptr[c], lBc + (w * 4 + c) * 1024);
            aptr[c] += 128;
            bptr[c] += 128;
        }
        __syncthreads();
#pragma unroll
        for (int ks = 0; ks < 2; ++ks) {
            bf16x8 af[4], bfr[4];
#pragma unroll
            for (int i = 0; i < 4; ++i) {
                int row = wr * 64 + i * 16 + (l & 15);
                int cb = (ks * 64 + (l >> 4) * 16) ^ ((row & 7) << 4);
                af[i] = *(const bf16x8*)(lAc + row * 128 + cb);
            }
#pragma unroll
            for (int j = 0; j < 4; ++j) {
                int row = wc * 64 + j * 16 + (l & 15);
                int cb = (ks * 64 + (l >> 4) * 16) ^ ((row & 7) << 4);
                bfr[j] = *(const bf16x8*)(lBc + row * 128 + cb);
            }
#pragma unroll
            for (int i = 0; i < 4; ++i)
#pragma unroll
                for (int j = 0; j < 4; ++j)
                    acc[i][j] = __builtin_amdgcn_mfma_f32_16x16x32_bf16(af[i], bfr[j], acc[i][j], 0, 0, 0);
        }
    }

    __syncthreads();   // all LDS tile reads done before epilogue reuses lA/lB
    epilogue_store(acc, bias, C, m0, n0, N, act, wr, wc, l,
                   (w < 2 ? lAc : lBc) + (w & 1) * 4608);
}

// ---------------- GEMM 128x128, BK=128 (+ ptr strength-reduction) ----------
__global__ __launch_bounds__(256) void gemm_bt128_kernel(
    const ushort_t* __restrict__ A, const ushort_t* __restrict__ Bt,
    const float* __restrict__ bias, ushort_t* __restrict__ C,
    int M, int N, int K, int act)
{
    __shared__ __align__(16) ushort_t lA[128 * 128];   // 32KB
    __shared__ __align__(16) ushort_t lB[128 * 128];   // 32KB
    const int t = threadIdx.x;
    const int w = t >> 6, l = t & 63;
    const int wr = w >> 1, wc = w & 1;
    const long m0 = (long)blockIdx.x * 128;
    const long n0 = (long)blockIdx.y * 128;

    const int srow = t >> 4;
    const int ssrc = ((t & 15) * 16) ^ ((srow & 7) << 4);

    f32x4 acc[4][4];
    f32x4 zf = {0.f, 0.f, 0.f, 0.f};
#pragma unroll
    for (int i = 0; i < 4; ++i)
#pragma unroll
        for (int j = 0; j < 4; ++j) acc[i][j] = zf;

    char* lAc = (char*)lA;
    char* lBc = (char*)lB;

    const char* aptr[8];
    const char* bptr[8];
#pragma unroll
    for (int r = 0; r < 8; ++r) {
        int row = r * 16 + srow;
        aptr[r] = (const char*)(A + (m0 + row) * (long)K) + ssrc;
        bptr[r] = (const char*)(Bt + (n0 + row) * (long)K) + ssrc;
    }

    for (int k0 = 0; k0 < K; k0 += 128) {
        __syncthreads();
#pragma unroll
        for (int r = 0; r < 8; ++r) {
            gload16(aptr[r], lAc + r * 4096 + t * 16);
            gload16(bptr[r], lBc + r * 4096 + t * 16);
            aptr[r] += 256;
            bptr[r] += 256;
        }
        __syncthreads();
#pragma unroll
        for (int ks = 0; ks < 4; ++ks) {
            bf16x8 af[4], bfr[4];
#pragma unroll
            for (int i = 0; i < 4; ++i) {
                int row = wr * 64 + i * 16 + (l & 15);
                int cb = (ks * 64 + (l >> 4) * 16) ^ ((row & 7) << 4);
                af[i] = *(const bf16x8*)(lAc + row * 256 + cb);
            }
#pragma unroll
            for (int j = 0; j < 4; ++j) {
                int row = wc * 64 + j * 16 + (l & 15);
                int cb = (ks * 64 + (l >> 4) * 16) ^ ((row & 7) << 4);
                bfr[j] = *(const bf16x8*)(lBc + row * 256 + cb);
            }
#pragma unroll
            for (int i = 0; i < 4; ++i)
#pragma unroll
                for (int j = 0; j < 4; ++j)
                    acc[i][j] = __builtin_amdgcn_mfma_f32_16x16x32_bf16(af[i], bfr[j], acc[i][j], 0, 0, 0);
        }
    }

    __syncthreads();
    epilogue_store(acc, bias, C, m0, n0, N, act, wr, wc, l,
                   (w < 2 ? lAc : lBc) + (w & 1) * 4608);
}

// ---------------- causal flash attention v2 (+ ptr strength-reduction) ----------
__global__ __launch_bounds__(512, 4) void attn_kernel(
    const ushort_t* __restrict__ qkv, ushort_t* __restrict__ o)
{
    __shared__ __align__(16) ushort_t lK[2 * 64 * 128];   // 32KB, 2 bufs, swizzled
    __shared__ __align__(16) ushort_t lVT[128 * 72];      // 18KB, V^T padded to 72
    __shared__ __align__(16) ushort_t lP[8 * 16 * 64];    // 16KB, per-wave P

    const int t = threadIdx.x, w = t >> 6, l = t & 63;
    const int bx = blockIdx.x;
    const int qblk = (bx & 1) ? (15 - (bx >> 1)) : (bx >> 1);
    const int bh = blockIdx.y;
    const int b = bh >> 4, h = bh & 15;
    const int q0 = qblk * 128 + w * 16;
    const long base = (long)b * 2048 * 6144 + (long)h * 128;
    char* lKc = (char*)lK;

    const ushort_t* qrow = qkv + base + (long)(q0 + (l & 15)) * 6144;
    bf16x8 qf[4];
#pragma unroll
    for (int hb = 0; hb < 4; ++hb)
        qf[hb] = *(const bf16x8*)(qrow + hb * 32 + (l >> 4) * 8);

    f32x4 accO[8];
    f32x4 zf = {0.f, 0.f, 0.f, 0.f};
#pragma unroll
    for (int i = 0; i < 8; ++i) accO[i] = zf;
    float m_r[4] = {-1e30f, -1e30f, -1e30f, -1e30f};
    float l_r[4] = {0.f, 0.f, 0.f, 0.f};

    const int nt = (qblk * 128 + 128) >> 6;
    const float scale = 0.08838834764831845f;
    const long TILE_ADV = 64L * 6144 * 2;   // bytes per kv tile

    const int kvp = t & 31;
    const int d0 = (t >> 5) * 8;
    us8 va, vb;

    // strength-reduced staging pointers
    const char* kptr[2];
#pragma unroll
    for (int i = 0; i < 2; ++i) {
        int c = w * 2 + i;
        int row = c * 4 + (l >> 4);
        int src = ((l & 15) * 16) ^ ((row & 7) << 4);
        kptr[i] = (const char*)(qkv + base + 2048 + (long)row * 6144) + src;
    }
    const char* vptr = (const char*)(qkv + base + 4096 + (long)(kvp * 2) * 6144 + d0);

    auto stageK = [&](int buf) {
#pragma unroll
        for (int i = 0; i < 2; ++i) {
            gload16(kptr[i], lKc + buf * 16384 + (w * 2 + i) * 1024);
            kptr[i] += TILE_ADV;
        }
    };
    auto loadV = [&]() {
        va = *(const us8*)vptr;
        vb = *(const us8*)(vptr + 6144 * 2);
        vptr += TILE_ADV;
    };
    auto writeVT = [&]() {
#pragma unroll
        for (int j = 0; j < 8; ++j) {
            unsigned pk = (unsigned)va[j] | ((unsigned)vb[j] << 16);
            *(unsigned*)(lVT + (d0 + j) * 72 + kvp * 2) = pk;
        }
    };

    stageK(0);
    loadV();
    asm volatile("s_waitcnt vmcnt(0)" ::: "memory");
    writeVT();
    __syncthreads();

    for (int t0 = 0; t0 < nt; ++t0) {
        const int cur = t0 & 1;
        const bool more = (t0 + 1 < nt);
        if (more) { stageK(cur ^ 1); loadV(); }

        const int kv0 = t0 * 64;
        if (kv0 <= q0 + 15) {
            f32x4 sc[4];
#pragma unroll
            for (int kvs = 0; kvs < 4; ++kvs) {
                sc[kvs] = zf;
                int row = kvs * 16 + (l & 15);
#pragma unroll
                for (int hb = 0; hb < 4; ++hb) {
                    int cb = (hb * 64 + (l >> 4) * 16) ^ ((row & 7) << 4);
                    bf16x8 kf = *(const bf16x8*)(lKc + cur * 16384 + row * 256 + cb);
                    sc[kvs] = __builtin_amdgcn_mfma_f32_16x16x32_bf16(qf[hb], kf, sc[kvs], 0, 0, 0);
                }
            }
#pragma unroll
            for (int r = 0; r < 4; ++r) {
                int qg = q0 + (l >> 4) * 4 + r;
                float s[4];
#pragma unroll
                for (int kvs = 0; kvs < 4; ++kvs) {
                    s[kvs] = sc[kvs][r] * scale;
                    if (kv0 + kvs * 16 + (l & 15) > qg) s[kvs] = -1e30f;
                }
                float pm = fmaxf(fmaxf(s[0], s[1]), fmaxf(s[2], s[3]));
                pm = fmaxf(pm, __shfl_xor(pm, 1));
                pm = fmaxf(pm, __shfl_xor(pm, 2));
                pm = fmaxf(pm, __shfl_xor(pm, 4));
                pm = fmaxf(pm, __shfl_xor(pm, 8));
                float mn = fmaxf(m_r[r], pm);
                float p[4], ps = 0.f;
#pragma unroll
                for (int kvs = 0; kvs < 4; ++kvs) { p[kvs] = __expf(s[kvs] - mn); ps += p[kvs]; }
                ps += __shfl_xor(ps, 1);
                ps += __shfl_xor(ps, 2);
                ps += __shfl_xor(ps, 4);
                ps += __shfl_xor(ps, 8);
                float alpha = __expf(m_r[r] - mn);
                l_r[r] = l_r[r] * alpha + ps;
                m_r[r] = mn;
#pragma unroll
                for (int tt = 0; tt < 8; ++tt) accO[tt][r] *= alpha;
                int qloc = (l >> 4) * 4 + r;
#pragma unroll
                for (int kvs = 0; kvs < 4; ++kvs)
                    lP[w * 1024 + qloc * 64 + kvs * 16 + (l & 15)] = f2bf(p[kvs]);
            }
            asm volatile("s_waitcnt lgkmcnt(0)" ::: "memory");
#pragma unroll
            for (int ks = 0; ks < 2; ++ks) {
                bf16x8 pf = *(const bf16x8*)(lP + w * 1024 + (l & 15) * 64 + ks * 32 + (l >> 4) * 8);
#pragma unroll
                for (int tt = 0; tt < 8; ++tt) {
                    bf16x8 vf = *(const bf16x8*)(lVT + (tt * 16 + (l & 15)) * 72 + ks * 32 + (l >> 4) * 8);
                    accO[tt] = __builtin_amdgcn_mfma_f32_16x16x32_bf16(pf, vf, accO[tt], 0, 0, 0);
                }
            }
        }

        asm volatile("s_waitcnt vmcnt(0)" ::: "memory");
        __syncthreads();
        if (more) { writeVT(); __syncthreads(); }
    }

    const long obase = (long)b * 2048 * 2048 + (long)h * 128;
#pragma unroll
    for (int r = 0; r < 4; ++r) {
        float inv = 1.f / l_r[r];
        long orow = obase + (long)(q0 + (l >> 4) * 4 + r) * 2048;
#pragma unroll
        for (int tt = 0; tt < 8; ++tt)
            o[orow + tt * 16 + (l & 15)] = f2bf(accO[tt][r] * inv);
    }
}

// ---------------- fused residual + LayerNorm (f32) ----------------
__global__ __launch_bounds__(256) void ln_kernel(
    const float* xres, const ushort_t* __restrict__ addb,
    const float* __restrict__ g, const float* __restrict__ bb,
    float* outf, ushort_t* __restrict__ outb)
{
    __shared__ float rs[4], rss[4];
    const int row = blockIdx.x, t = threadIdx.x;
    const float* xp = xres + (long)row * 2048 + t * 8;
    const ushort_t* ap = addb + (long)row * 2048 + t * 8;
    float4 a = *(const float4*)xp;
    float4 c = *(const float4*)(xp + 4);
    us8 ad = *(const us8*)ap;
    float v[8];
    v[0] = a.x + bf2f(ad[0]); v[1] = a.y + bf2f(ad[1]);
    v[2] = a.z + bf2f(ad[2]); v[3] = a.w + bf2f(ad[3]);
    v[4] = c.x + bf2f(ad[4]); v[5] = c.y + bf2f(ad[5]);
    v[6] = c.z + bf2f(ad[6]); v[7] = c.w + bf2f(ad[7]);
    float s = 0.f, ss = 0.f;
#pragma unroll
    for (int j = 0; j < 8; ++j) { s += v[j]; ss += v[j] * v[j]; }
#pragma unroll
    for (int off = 32; off > 0; off >>= 1) {
        s += __shfl_down(s, off);
        ss += __shfl_down(ss, off);
    }
    if ((t & 63) == 0) { rs[t >> 6] = s; rss[t >> 6] = ss; }
    __syncthreads();
    float S = rs[0] + rs[1] + rs[2] + rs[3];
    float SS = rss[0] + rss[1] + rss[2] + rss[3];
    float mean = S * (1.f / 2048.f);
    float var = SS * (1.f / 2048.f) - mean * mean;
    float rstd = rsqrtf(var + 1e-8f);
    float of[8];
#pragma unroll
    for (int j = 0; j < 8; ++j) {
        int col = t * 8 + j;
        of[j] = (v[j] - mean) * rstd * g[col] + bb[col];
    }
    float4 o1 = {of[0], of[1], of[2], of[3]};
    float4 o2 = {of[4], of[5], of[6], of[7]};
    float* op = outf + (long)row * 2048 + t * 8;
    *(float4*)op = o1;
    *(float4*)(op + 4) = o2;
    if (outb) {
        us8 ob;
#pragma unroll
        for (int j = 0; j < 8; ++j) ob[j] = f2bf(of[j]);
        *(us8*)(outb + (long)row * 2048 + t * 8) = ob;
    }
}

extern "C" void kernel_launch(void* const* d_in, const int* in_sizes, int n_in,
                              void* d_out, int out_size, void* d_ws, size_t ws_size,
                              hipStream_t stream)
{
    const float* x  = (const float*)d_in[0];
    const float* wq = (const float*)d_in[1];
    const float* bq = (const float*)d_in[2];
    const float* wk = (const float*)d_in[3];
    const float* bk = (const float*)d_in[4];
    const float* wv = (const float*)d_in[5];
    const float* bv = (const float*)d_in[6];
    const float* wo = (const float*)d_in[7];
    const float* bo = (const float*)d_in[8];
    const float* g1 = (const float*)d_in[9];
    const float* b1 = (const float*)d_in[10];
    const float* wu = (const float*)d_in[11];
    const float* bu = (const float*)d_in[12];
    const float* wd = (const float*)d_in[13];
    const float* bd = (const float*)d_in[14];
    const float* g2 = (const float*)d_in[15];
    const float* b2 = (const float*)d_in[16];
    (void)in_sizes; (void)n_in; (void)out_size;

    // ---- slot-based workspace (sequential lifetime reuse), total 112MB+32KB ----
    const size_t MB = 1ull << 20;
    char* wsp = (char*)d_ws;
    char*  slotA = wsp;                 // 32MB: qkvT(24) -> woT(8) -> wuT(32) -> wdT(32)
    char*  slotB = wsp + 32 * MB;       // 16MB: xb -> ab -> x1b -> db
    char*  slotC = wsp + 48 * MB;       // 64MB: qkvb(48) -> pb(16) -> hb(64)
    float* bqkv  = (float*)(wsp + 112 * MB); // 24KB
    const size_t need = 112 * MB + 32768;
    if (ws_size < need) {
        fill_kernel<<<(8388608 + 255) / 256, 256, 0, stream>>>((float*)d_out, 8388608L, 1e6f);
        return;
    }

    ushort_t* xb   = (ushort_t*)slotB;             // [4096][2048] bf16
    ushort_t* wT   = (ushort_t*)slotA;             // current transposed weight
    ushort_t* qkvb = (ushort_t*)slotC;             // [4096][6144]
    ushort_t* ab   = (ushort_t*)slotB;             // [4096][2048]
    ushort_t* pb   = (ushort_t*)slotC;             // [4096][2048]
    float*    x1f  = (float*)d_out;                // [4096][2048] f32 (borrow d_out)
    ushort_t* x1b  = (ushort_t*)slotB;             // [4096][2048]
    ushort_t* hb   = (ushort_t*)slotC;             // [4096][8192]
    ushort_t* db   = (ushort_t*)slotB;             // [4096][2048]

    // 1) cast x -> bf16
    cast_bf16_kernel<<<8192, 256, 0, stream>>>(x, xb, 8388608L);
    // 2) merged transpose wq|wk|wv -> wT (24MB), pack biases
    transpose3_bf16_kernel<<<dim3(64, 64, 3), 256, 0, stream>>>(wq, wk, wv, wT);
    hipMemcpyAsync(bqkv,        bq, 2048 * sizeof(float), hipMemcpyDeviceToDevice, stream);
    hipMemcpyAsync(bqkv + 2048, bk, 2048 * sizeof(float), hipMemcpyDeviceToDevice, stream);
    hipMemcpyAsync(bqkv + 4096, bv, 2048 * sizeof(float), hipMemcpyDeviceToDevice, stream);
    // 3) fused QKV projection: [4096,2048]@[2048,6144] (2D grid, BK=64)
    gemm_bt_kernel<<<dim3(32, 48), 256, 0, stream>>>(xb, wT, bqkv, qkvb, 4096, 6144, 2048, 0);
    // 4) causal attention
    attn_kernel<<<dim3(16, 32), 512, 0, stream>>>(qkvb, ab);
    // 5) transpose wo -> wT
    transpose_bf16_kernel<<<dim3(64, 64), 256, 0, stream>>>(wo, wT, 2048, 2048);
    // 6) output projection (grid-limited: BK=128, 2D grid)
    gemm_bt128_kernel<<<dim3(32, 16), 256, 0, stream>>>(ab, wT, bo, pb, 4096, 2048, 2048, 0);
    // 7) residual + LN1 -> x1f (in d_out) + x1b
    ln_kernel<<<4096, 256, 0, stream>>>(x, pb, g1, b1, x1f, x1b);
    // 8) transpose wu -> wT
    transpose_bf16_kernel<<<dim3(256, 64), 256, 0, stream>>>(wu, wT, 2048, 8192);
    // 9) FFN up + exact GELU (2D grid, BK=64)
    gemm_bt_kernel<<<dim3(32, 64), 256, 0, stream>>>(x1b, wT, bu, hb, 4096, 8192, 2048, 1);
    // 10) transpose wd -> wT
    transpose_bf16_kernel<<<dim3(64, 256), 256, 0, stream>>>(wd, wT, 8192, 2048);
    // 11) FFN down (K=8192, grid-limited: BK=128, 2D grid)
    gemm_bt128_kernel<<<dim3(32, 16), 256, 0, stream>>>(hb, wT, bd, db, 4096, 2048, 8192, 0);
    // 12) residual + LN2 (reads x1f from d_out, writes d_out in place)
    ln_kernel<<<4096, 256, 0, stream>>>(x1f, db, g2, b2, (float*)d_out, nullptr);
}